// Round 1
// baseline (436.723 us; speedup 1.0000x reference)
//
#include <hip/hip_runtime.h>

// Shapes (fixed per setup_inputs): n=1, C=256, t=8, h=64, w=64, heads=8, S=134
#define SS   134
#define WW2  64
#define HWP  4096     // h*w
#define THW  32768    // t*h*w

__device__ __forceinline__ float vget(const float4& v, int j) {
  return j == 0 ? v.x : j == 1 ? v.y : j == 2 ? v.z : v.w;
}

// ---------------------------------------------------------------------------
// 1x1 conv as GEMM: PV[o][x] = sum_c W[o][c] * V[c][x] + bias[o]
// M=256 (o), K=256 (c), N=32768 (x). 64x64 tile, 4x4 micro, K-chunk 16.
// ---------------------------------------------------------------------------
__global__ __launch_bounds__(256) void conv1x1_kernel(
    const float* __restrict__ V, const float* __restrict__ W,
    const float* __restrict__ bias, float* __restrict__ PV) {
  __shared__ float sW[16][68];  // [k][o], stride 68: 16B-aligned rows, bank-skewed
  __shared__ float sV[16][64];  // [k][x]
  const int tid = threadIdx.x;
  const int xb = blockIdx.x;  // 512
  const int ob = blockIdx.y;  // 4
  const int tx = tid & 15;
  const int ty = tid >> 4;
  const int x0 = xb * 64;
  float acc[4][4] = {};

  const int wo = tid >> 2;        // 0..63  (o row for W staging)
  const int wk = (tid & 3) << 2;  // 0,4,8,12 (k quad for W staging)

  for (int k0 = 0; k0 < 256; k0 += 16) {
    const float4 wv = *(const float4*)&W[(size_t)(ob * 64 + wo) * 256 + k0 + wk];
    const float4 vv = *(const float4*)&V[(size_t)(k0 + ty) * THW + x0 + tx * 4];
    sW[wk + 0][wo] = wv.x;
    sW[wk + 1][wo] = wv.y;
    sW[wk + 2][wo] = wv.z;
    sW[wk + 3][wo] = wv.w;
    *(float4*)&sV[ty][tx * 4] = vv;
    __syncthreads();
#pragma unroll
    for (int k = 0; k < 16; ++k) {
      const float4 wq = *(const float4*)&sW[k][ty * 4];
      const float4 vq = *(const float4*)&sV[k][tx * 4];
#pragma unroll
      for (int i = 0; i < 4; ++i)
#pragma unroll
        for (int j = 0; j < 4; ++j)
          acc[i][j] += vget(wq, i) * vget(vq, j);
    }
    __syncthreads();
  }
#pragma unroll
  for (int i = 0; i < 4; ++i) {
    const int o = ob * 64 + ty * 4 + i;
    const float b = bias[o];
    float4 r;
    r.x = acc[i][0] + b;
    r.y = acc[i][1] + b;
    r.z = acc[i][2] + b;
    r.w = acc[i][3] + b;
    *(float4*)&PV[(size_t)o * THW + x0 + tx * 4] = r;
  }
}

// ---------------------------------------------------------------------------
// Criss-cross attention aggregation.
// Block = (hd, tq, hq-tile of 4). 256 threads: lane -> (c0 = tid>>4 in 0..15
// handling channels {c0, c0+16}, wq4 = (tid&15)*4 handling 4 w positions).
// acc[2 chan][4 hq][4 wq].
//   t-axis: out += A[s, tq,hq,wq] * pv[c, s, hq, wq]            (s = 0..7)
//   h-axis: out += A[8+idx, ...]  * pv[c, tq, p, wq]  idx=p<hq?p:p-1, p!=hq
//   w-axis (by weight row r=0..62): out[wq] += A[71+r, ...] * pv[c,tq,hq,p],
//           p = r<wq ? r : r+1  -> rolling pair from LDS-staged w-slice.
// ---------------------------------------------------------------------------
__global__ __launch_bounds__(256, 4) void grid_attn_kernel(
    const float* __restrict__ A, const float* __restrict__ PV,
    float* __restrict__ O) {
  const int blk = blockIdx.x;  // hqb + 16*(tq + 8*hd), grid 1024
  const int hq0 = (blk & 15) * 4;
  const int tq = (blk >> 4) & 7;
  const int hd = blk >> 7;
  const int tid = threadIdx.x;
  const int wq4 = (tid & 15) * 4;
  const int c0 = tid >> 4;  // 0..15

  const float* __restrict__ Ab = A + (size_t)hd * SS * THW + (size_t)tq * HWP;
  const float* __restrict__ PVh = PV + (size_t)hd * 32 * THW;
  float* __restrict__ Oh = O + (size_t)hd * 32 * THW;

  __shared__ float sPVw[32 * 4 * 68];  // [c][q][p], row stride 68 (aligned+skewed)

  // stage w-slices: pv[c, tq, hq0+q, p] for c=0..31, q=0..3, p=0..63
  {
    const int c = tid >> 3;          // 0..31
    const int q = (tid >> 1) & 3;    // 0..3
    const int p0 = (tid & 1) * 32;   // 0,32
    const float* src = &PVh[(size_t)c * THW + (size_t)tq * HWP + (hq0 + q) * WW2 + p0];
    float* dst = &sPVw[(c * 4 + q) * 68 + p0];
#pragma unroll
    for (int i = 0; i < 8; ++i)
      *(float4*)(dst + i * 4) = *(const float4*)(src + i * 4);
  }
  __syncthreads();

  float acc[2][4][4] = {};

  // ---- t axis ----
#pragma unroll
  for (int s = 0; s < 8; ++s) {
#pragma unroll
    for (int q = 0; q < 4; ++q) {
      const int hq = hq0 + q;
      const float4 a = *(const float4*)&Ab[(size_t)s * THW + hq * WW2 + wq4];
      const float4 v0 = *(const float4*)&PVh[(size_t)c0 * THW + (size_t)s * HWP + hq * WW2 + wq4];
      const float4 v1 = *(const float4*)&PVh[(size_t)(c0 + 16) * THW + (size_t)s * HWP + hq * WW2 + wq4];
#pragma unroll
      for (int j = 0; j < 4; ++j) {
        acc[0][q][j] += vget(a, j) * vget(v0, j);
        acc[1][q][j] += vget(a, j) * vget(v1, j);
      }
    }
  }

  // ---- h axis ----
  for (int p = 0; p < 64; ++p) {
    const float4 v0 = *(const float4*)&PVh[(size_t)c0 * THW + (size_t)tq * HWP + p * WW2 + wq4];
    const float4 v1 = *(const float4*)&PVh[(size_t)(c0 + 16) * THW + (size_t)tq * HWP + p * WW2 + wq4];
#pragma unroll
    for (int q = 0; q < 4; ++q) {
      const int hq = hq0 + q;
      if (p == hq) continue;  // block-uniform branch
      const int idx = (p < hq) ? p : p - 1;
      const float4 a = *(const float4*)&Ab[(size_t)(8 + idx) * THW + hq * WW2 + wq4];
#pragma unroll
      for (int j = 0; j < 4; ++j) {
        acc[0][q][j] += vget(a, j) * vget(v0, j);
        acc[1][q][j] += vget(a, j) * vget(v1, j);
      }
    }
  }

  // ---- w axis (iterate weight rows, rolling source pair from LDS) ----
  float cur[2][4], nxt[2][4];
#pragma unroll
  for (int q = 0; q < 4; ++q) {
    cur[0][q] = sPVw[(c0 * 4 + q) * 68];
    cur[1][q] = sPVw[((c0 + 16) * 4 + q) * 68];
  }
  for (int r = 0; r < 63; ++r) {
#pragma unroll
    for (int q = 0; q < 4; ++q) {
      nxt[0][q] = sPVw[(c0 * 4 + q) * 68 + r + 1];
      nxt[1][q] = sPVw[((c0 + 16) * 4 + q) * 68 + r + 1];
    }
#pragma unroll
    for (int q = 0; q < 4; ++q) {
      const int hq = hq0 + q;
      const float4 a = *(const float4*)&Ab[(size_t)(71 + r) * THW + hq * WW2 + wq4];
#pragma unroll
      for (int j = 0; j < 4; ++j) {
        const float w = vget(a, j);
        const bool lt = (r < wq4 + j);  // source p = lt ? r : r+1
        acc[0][q][j] += w * (lt ? cur[0][q] : nxt[0][q]);
        acc[1][q][j] += w * (lt ? cur[1][q] : nxt[1][q]);
      }
    }
#pragma unroll
    for (int q = 0; q < 4; ++q) {
      cur[0][q] = nxt[0][q];
      cur[1][q] = nxt[1][q];
    }
  }

  // ---- store ----
#pragma unroll
  for (int ch = 0; ch < 2; ++ch) {
    const int c = ch ? (c0 + 16) : c0;
#pragma unroll
    for (int q = 0; q < 4; ++q) {
      float4 r;
      r.x = acc[ch][q][0];
      r.y = acc[ch][q][1];
      r.z = acc[ch][q][2];
      r.w = acc[ch][q][3];
      *(float4*)&Oh[(size_t)c * THW + (size_t)tq * HWP + (hq0 + q) * WW2 + wq4] = r;
    }
  }
}

extern "C" void kernel_launch(void* const* d_in, const int* in_sizes, int n_in,
                              void* d_out, int out_size, void* d_ws, size_t ws_size,
                              hipStream_t stream) {
  const float* A = (const float*)d_in[0];     // [8*134][8][64][64]
  const float* V = (const float*)d_in[1];     // [256][8][64][64]
  const float* W = (const float*)d_in[2];     // [256][256] (o, c)
  const float* bias = (const float*)d_in[3];  // [256]
  float* out = (float*)d_out;                 // [256][8][64][64]
  float* pv = (float*)d_ws;                   // 32 MB scratch: pv[o][t][h][w]

  conv1x1_kernel<<<dim3(512, 4), 256, 0, stream>>>(V, W, bias, pv);
  grid_attn_kernel<<<dim3(1024), 256, 0, stream>>>(A, pv, out);
}

// Round 2
// 392.582 us; speedup vs baseline: 1.1124x; 1.1124x over previous
//
#include <hip/hip_runtime.h>

// Shapes (fixed per setup_inputs): n=1, C=256, t=8, h=64, w=64, heads=8, S=134
#define SS   134
#define HWP  4096     // h*w
#define THW  32768    // t*h*w

typedef float f32x4 __attribute__((ext_vector_type(4)));
typedef short bf16x8 __attribute__((ext_vector_type(8)));
typedef short bf16x4 __attribute__((ext_vector_type(4)));

__device__ __forceinline__ float vget(const float4& v, int j) {
  return j == 0 ? v.x : j == 1 ? v.y : j == 2 ? v.z : v.w;
}

__device__ __forceinline__ unsigned short f2bf(float f) {
  unsigned int u = __float_as_uint(f);
  u += 0x7fff + ((u >> 16) & 1);  // RNE (inputs are finite normals)
  return (unsigned short)(u >> 16);
}

// ---------------------------------------------------------------------------
// 1x1 conv as bf16-MFMA GEMM: PV[o][x] = sum_c W[o][c] * V[c][x] + bias[o]
// M=256 (o, full per block), N=32 (x per block), K=256 in chunks of 32.
// Grid 1024 (= 4 blocks/CU). 256 thr = 4 waves; wave w: o-range [w*64,w*64+64).
// Per wave per chunk: 4 a-frag + 2 b-frag ds_read_b128 + 8 MFMA 16x16x32.
// LDS rows padded to 40 bf16 (80 B) -> 16B-aligned b128 reads, 2-way banks (free).
// ---------------------------------------------------------------------------
__global__ __launch_bounds__(256, 4) void conv1x1_mfma(
    const float* __restrict__ V, const float* __restrict__ W,
    const float* __restrict__ bias, float* __restrict__ PV) {
  __shared__ unsigned short sW[256 * 40];  // [o][c-k0], bf16
  __shared__ unsigned short sV[32 * 40];   // [x][c-k0], bf16 (transposed)
  const int tid = threadIdx.x;
  const int x0 = blockIdx.x * 32;
  const int lane = tid & 63;
  const int wv = tid >> 6;   // wave 0..3
  const int m = lane & 15;   // MFMA free-dim index
  const int q = lane >> 4;   // MFMA quad 0..3

  f32x4 acc[4][2];
#pragma unroll
  for (int i = 0; i < 4; ++i)
#pragma unroll
    for (int j = 0; j < 2; ++j)
      acc[i][j] = (f32x4){0.f, 0.f, 0.f, 0.f};

  for (int k0 = 0; k0 < 256; k0 += 32) {
    // stage W chunk: 256 o x 32 c fp32 -> bf16 LDS [o][c] (coalesced reads)
#pragma unroll
    for (int r = 0; r < 8; ++r) {
      const int f = r * 256 + tid;
      const int o = f >> 3;
      const int c4 = (f & 7) * 4;
      const float4 w4 = *(const float4*)&W[o * 256 + k0 + c4];
      bf16x4 b;
      b.x = (short)f2bf(w4.x);
      b.y = (short)f2bf(w4.y);
      b.z = (short)f2bf(w4.z);
      b.w = (short)f2bf(w4.w);
      *(bf16x4*)&sW[o * 40 + c4] = b;
    }
    // stage V chunk: 32 c x 32 x fp32 -> transposed bf16 LDS [x][c]
    {
      const int c = tid >> 3;          // 0..31
      const int x4 = (tid & 7) * 4;    // 0..28
      const float4 v4 = *(const float4*)&V[(size_t)(k0 + c) * THW + x0 + x4];
      sV[(x4 + 0) * 40 + c] = f2bf(v4.x);
      sV[(x4 + 1) * 40 + c] = f2bf(v4.y);
      sV[(x4 + 2) * 40 + c] = f2bf(v4.z);
      sV[(x4 + 3) * 40 + c] = f2bf(v4.w);
    }
    __syncthreads();
    bf16x8 fa[4], fb[2];
#pragma unroll
    for (int i = 0; i < 4; ++i)
      fa[i] = *(const bf16x8*)&sW[(wv * 64 + i * 16 + m) * 40 + q * 8];
#pragma unroll
    for (int j = 0; j < 2; ++j)
      fb[j] = *(const bf16x8*)&sV[(j * 16 + m) * 40 + q * 8];
#pragma unroll
    for (int i = 0; i < 4; ++i)
#pragma unroll
      for (int j = 0; j < 2; ++j)
        acc[i][j] = __builtin_amdgcn_mfma_f32_16x16x32_bf16(fa[i], fb[j], acc[i][j], 0, 0, 0);
    __syncthreads();
  }

  // epilogue: D[row=q*4+r][col=m] per 16x16 tile; add bias, store fp32
#pragma unroll
  for (int i = 0; i < 4; ++i) {
#pragma unroll
    for (int r = 0; r < 4; ++r) {
      const int o = wv * 64 + i * 16 + q * 4 + r;
      const float b = bias[o];
#pragma unroll
      for (int j = 0; j < 2; ++j)
        PV[(size_t)o * THW + x0 + j * 16 + m] = acc[i][j][r] + b;
    }
  }
}

// ---------------------------------------------------------------------------
// Criss-cross attention aggregation. HQ_TILE=2 (LDS 17.4 kB -> 8 blocks/CU).
// Block = (hd, tq, hq-pair). 256 threads: c0 = tid>>4 handles {c0, c0+16},
// wq4 = (tid&15)*4 handles 4 w. acc[2 ch][2 hq][4 wq] = 16 VGPRs.
// h-axis loop is branch-free (mask-multiply for p==hq) and unrolled x2.
// ---------------------------------------------------------------------------
__global__ __launch_bounds__(256, 8) void grid_attn_kernel(
    const float* __restrict__ A, const float* __restrict__ PV,
    float* __restrict__ O) {
  const int blk = blockIdx.x;  // hqb + 32*(tq + 8*hd), grid 2048
  const int hq0 = (blk & 31) * 2;
  const int tq = (blk >> 5) & 7;
  const int hd = blk >> 8;
  const int tid = threadIdx.x;
  const int wq4 = (tid & 15) * 4;
  const int c0 = tid >> 4;  // 0..15

  const float* __restrict__ Ab = A + (size_t)hd * SS * THW + (size_t)tq * HWP;
  const float* __restrict__ PVh = PV + (size_t)hd * 32 * THW;
  float* __restrict__ Oh = O + (size_t)hd * 32 * THW;

  __shared__ float sPVw[32 * 2 * 68];  // [c][q][p], row stride 68

  // stage w-slices: pv[c, tq, hq0+q, p] for c=0..31, q=0..1, p=0..63
  {
    const int c = tid >> 3;         // 0..31
    const int q = (tid >> 2) & 1;   // 0..1
    const int p0 = (tid & 3) * 16;  // 0,16,32,48
    const float* src = &PVh[(size_t)c * THW + (size_t)tq * HWP + (hq0 + q) * 64 + p0];
    float* dst = &sPVw[(c * 2 + q) * 68 + p0];
#pragma unroll
    for (int i = 0; i < 4; ++i)
      *(float4*)(dst + i * 4) = *(const float4*)(src + i * 4);
  }
  __syncthreads();

  float acc[2][2][4] = {};

  // ---- t axis ----
#pragma unroll
  for (int s = 0; s < 8; ++s) {
#pragma unroll
    for (int q = 0; q < 2; ++q) {
      const int hq = hq0 + q;
      const float4 a = *(const float4*)&Ab[(size_t)s * THW + hq * 64 + wq4];
      const float4 v0 = *(const float4*)&PVh[(size_t)c0 * THW + (size_t)s * HWP + hq * 64 + wq4];
      const float4 v1 = *(const float4*)&PVh[(size_t)(c0 + 16) * THW + (size_t)s * HWP + hq * 64 + wq4];
#pragma unroll
      for (int j = 0; j < 4; ++j) {
        acc[0][q][j] += vget(a, j) * vget(v0, j);
        acc[1][q][j] += vget(a, j) * vget(v1, j);
      }
    }
  }

  // ---- h axis (branch-free, unrolled) ----
#pragma unroll 2
  for (int p = 0; p < 64; ++p) {
    const float4 v0 = *(const float4*)&PVh[(size_t)c0 * THW + (size_t)tq * HWP + p * 64 + wq4];
    const float4 v1 = *(const float4*)&PVh[(size_t)(c0 + 16) * THW + (size_t)tq * HWP + p * 64 + wq4];
#pragma unroll
    for (int q = 0; q < 2; ++q) {
      const int hq = hq0 + q;
      const int idx = (p < hq) ? p : (p > 0 ? p - 1 : 0);  // p==hq masked below
      const float msk = (p == hq) ? 0.f : 1.f;
      const float4 a = *(const float4*)&Ab[(size_t)(8 + idx) * THW + hq * 64 + wq4];
#pragma unroll
      for (int j = 0; j < 4; ++j) {
        const float w = vget(a, j) * msk;
        acc[0][q][j] += w * vget(v0, j);
        acc[1][q][j] += w * vget(v1, j);
      }
    }
  }

  // ---- w axis (weight rows r, rolling source pair from LDS) ----
  float cur[2][2], nxt[2][2];
#pragma unroll
  for (int q = 0; q < 2; ++q) {
    cur[0][q] = sPVw[(c0 * 2 + q) * 68];
    cur[1][q] = sPVw[((c0 + 16) * 2 + q) * 68];
  }
  for (int r = 0; r < 63; ++r) {
#pragma unroll
    for (int q = 0; q < 2; ++q) {
      nxt[0][q] = sPVw[(c0 * 2 + q) * 68 + r + 1];
      nxt[1][q] = sPVw[((c0 + 16) * 2 + q) * 68 + r + 1];
    }
#pragma unroll
    for (int q = 0; q < 2; ++q) {
      const int hq = hq0 + q;
      const float4 a = *(const float4*)&Ab[(size_t)(71 + r) * THW + hq * 64 + wq4];
#pragma unroll
      for (int j = 0; j < 4; ++j) {
        const float w = vget(a, j);
        const bool lt = (r < wq4 + j);  // source p = lt ? r : r+1
        acc[0][q][j] += w * (lt ? cur[0][q] : nxt[0][q]);
        acc[1][q][j] += w * (lt ? cur[1][q] : nxt[1][q]);
      }
    }
#pragma unroll
    for (int q = 0; q < 2; ++q) {
      cur[0][q] = nxt[0][q];
      cur[1][q] = nxt[1][q];
    }
  }

  // ---- store ----
#pragma unroll
  for (int ch = 0; ch < 2; ++ch) {
    const int c = ch ? (c0 + 16) : c0;
#pragma unroll
    for (int q = 0; q < 2; ++q) {
      float4 r;
      r.x = acc[ch][q][0];
      r.y = acc[ch][q][1];
      r.z = acc[ch][q][2];
      r.w = acc[ch][q][3];
      *(float4*)&Oh[(size_t)c * THW + (size_t)tq * HWP + (hq0 + q) * 64 + wq4] = r;
    }
  }
}

extern "C" void kernel_launch(void* const* d_in, const int* in_sizes, int n_in,
                              void* d_out, int out_size, void* d_ws, size_t ws_size,
                              hipStream_t stream) {
  const float* A = (const float*)d_in[0];     // [8*134][8][64][64]
  const float* V = (const float*)d_in[1];     // [256][8][64][64]
  const float* W = (const float*)d_in[2];     // [256][256] (o, c)
  const float* bias = (const float*)d_in[3];  // [256]
  float* out = (float*)d_out;                 // [256][8][64][64]
  float* pv = (float*)d_ws;                   // 32 MB scratch: pv[o][t][h][w]

  conv1x1_mfma<<<dim3(1024), 256, 0, stream>>>(V, W, bias, pv);
  grid_attn_kernel<<<dim3(2048), 256, 0, stream>>>(A, pv, out);
}